// Round 5
// baseline (371.123 us; speedup 1.0000x reference)
//
#include <hip/hip_runtime.h>

#define T_STEPS 1024
#define CC 6
#define NCHUNK 8                   // time chunks per row
#define NQ (NCHUNK / 2)            // chunk-PAIRS per row (ILP=2 per group)
#define CHUNK (T_STEPS / NCHUNK)   // 128
#define WARM 16                    // warm-up steps per chunk (error ~0.08^15)
#define KBUF 16                    // steps buffered in LDS before each flush
#define NBLK (CHUNK / KBUF)        // 8 flush blocks per chunk
#define GPAD 100                   // dwords per chain-buffer (96 used + 4 pad)
#define LOG2E 1.4426950408889634f
#define LN2   0.6931471805599453f

__device__ __forceinline__ float fexp2(float x) {
#if __has_builtin(__builtin_amdgcn_exp2f)
    return __builtin_amdgcn_exp2f(x);
#else
    return exp2f(x);
#endif
}

__device__ __forceinline__ float flog2(float x) {
#if __has_builtin(__builtin_amdgcn_logf)
    return __builtin_amdgcn_logf(x);   // v_log_f32 = log2
#else
    return log2f(x);
#endif
}

// One 8-lane group per (batch row, chunk-PAIR). Lane j (0..5) owns channel j;
// lanes 6,7 shadow lane 5 (identical math, same-address LDS writes) -> no
// divergence. Each group advances TWO independent recurrences (chunks 2q and
// 2q+1) in interleave: rounds 3/4 showed the binding cost is the ~120-cyc LDS
// round-trip (state write -> next-step read) in the serial chain -- with one
// chain per wave, all waves stall on lgkmcnt together (VALUBusy pinned ~45%).
// Chain B's compute fills chain A's LDS latency and vice versa.
//
// Chunks c>0 warm up WARM steps seeded with state = x at t0-WARM: per-step
// contraction (1-a)*max(Tn) ~ 0.08 -> seed error < 1e-16 by chunk start.
// Output buffered KBUF=16 steps/chain (384 B, 128-aligned) and flushed as
// 3 full-line dwordx4 stores per chain (round-3 fix for write amplification).
__global__ __launch_bounds__(256, 4) void transfer_kernel(
    const float* __restrict__ feats,
    const float* __restrict__ alpha,
    const float* __restrict__ trans,
    float* __restrict__ out, int B)
{
    __shared__ float sbuf[32 * 2 * GPAD];   // 32 groups * 2 chains * 400 B = 25.6 KB

    int tid = blockIdx.x * blockDim.x + threadIdx.x;
    int g   = tid >> 3;                 // global group id in [0, B*NQ)
    int gb  = (threadIdx.x >> 3);       // group id within block (0..31)
    int j   = tid & 7;
    int jl  = j < CC ? j : (CC - 1);
    if (g >= B * NQ) return;

    int b = g % B;   // consecutive groups -> consecutive rows (coalesced reads)
    int q = g / B;   // wave-uniform pair index (B % 8 == 0 -> no wave straddles)

    // a = sigmoid(alpha)
    float a  = 1.0f / (1.0f + fexp2(-alpha[0] * LOG2E));
    float c1 = (1.0f - a) * LN2;   // (1-a) * ln2: converts log2-sum to natural te

    // column jl of row-softmax(trans), pre-scaled by log2e
    float tcol[CC];
#pragma unroll
    for (int i = 0; i < CC; ++i) {
        float rs = 0.0f;
#pragma unroll
        for (int k = 0; k < CC; ++k)
            rs += fexp2(trans[i * CC + k] * LOG2E);
        tcol[i] = (fexp2(trans[i * CC + jl] * LOG2E) / rs) * LOG2E;
    }

    const float* fb = feats + (size_t)b * T_STEPS * CC;
    float*       ob = out   + (size_t)b * T_STEPS * CC;
    float* sgA = &sbuf[gb * 2 * GPAD];   // chain A LDS buffer
    float* sgB = sgA + GPAD;             // chain B LDS buffer

    // read previous step's state vector from LDS slot PSLOT of buffer SG,
    // advance chain state ST by one step. All addresses 8-B aligned.
#define STEP_LDS(SG, PSLOT, ST, xv)                                       \
    do {                                                                  \
        float2 s01 = *reinterpret_cast<const float2*>(&(SG)[(PSLOT) * CC + 0]); \
        float2 s23 = *reinterpret_cast<const float2*>(&(SG)[(PSLOT) * CC + 2]); \
        float2 s45 = *reinterpret_cast<const float2*>(&(SG)[(PSLOT) * CC + 4]); \
        float sum;                                                        \
        sum  = fexp2(s01.x * tcol[0]);                                    \
        sum += fexp2(s01.y * tcol[1]);                                    \
        sum += fexp2(s23.x * tcol[2]);                                    \
        sum += fexp2(s23.y * tcol[3]);                                    \
        sum += fexp2(s45.x * tcol[4]);                                    \
        sum += fexp2(s45.y * tcol[5]);                                    \
        (ST) = a * (xv) + c1 * flog2(sum);                                \
    } while (0)

    int t0A = (2 * q) * CHUNK;       // chain A chunk start
    int t0B = t0A + CHUNK;           // chain B chunk start (always > 0)
    float stA, stB;

    // ---- warm-up (interleaved when both chains warm) ----
    if (q != 0) {
        int twA = t0A - WARM, twB = t0B - WARM;   // >= 112, in-bounds
        stA = fb[twA * CC + jl];  sgA[jl] = stA;
        stB = fb[twB * CC + jl];  sgB[jl] = stB;
#pragma unroll
        for (int w = 1; w < WARM; ++w) {
            float xA = fb[(twA + w) * CC + jl];
            float xB = fb[(twB + w) * CC + jl];
            STEP_LDS(sgA, w - 1, stA, xA);  sgA[w * CC + jl] = stA;
            STEP_LDS(sgB, w - 1, stB, xB);  sgB[w * CC + jl] = stB;
        }
    } else {
        // chain A is chunk 0 (exact init inside main loop); warm B alone
        int twB = t0B - WARM;
        stB = fb[twB * CC + jl];  sgB[jl] = stB;
#pragma unroll
        for (int w = 1; w < WARM; ++w) {
            float xB = fb[(twB + w) * CC + jl];
            STEP_LDS(sgB, w - 1, stB, xB);  sgB[w * CC + jl] = stB;
        }
    }
    // after warm-up, state for (chunk_start - 1) sits in slot WARM-1 = KBUF-1

    // ---- main loop: both chains interleaved, flush every KBUF steps ----
#pragma unroll 1
    for (int kb = 0; kb < NBLK; ++kb) {
        int tbA = t0A + kb * KBUF;
        int tbB = t0B + kb * KBUF;

#pragma unroll
        for (int kk = 0; kk < KBUF; ++kk) {
            float xA = fb[(tbA + kk) * CC + jl];
            float xB = fb[(tbB + kk) * CC + jl];
            int ps = (kk == 0) ? (KBUF - 1) : (kk - 1);
            if (kk == 0 && kb == 0 && q == 0) {
                stA = xA;                       // t = 0: emit feats as-is
            } else {
                STEP_LDS(sgA, ps, stA, xA);
            }
            sgA[kk * CC + jl] = stA;            // lanes 6,7: same addr+value as 5
            STEP_LDS(sgB, ps, stB, xB);
            sgB[kk * CC + jl] = stB;
        }

        // flush both chains: 96 dwords each = 3 x (8 lanes x float4), every
        // store a full 128-B-aligned line. DS pipe in-order per wave -> no bar.
#pragma unroll
        for (int k = 0; k < 3; ++k) {
            int idx = (k * 8 + j) * 4;          // dword within the 96
            float4 vA = *reinterpret_cast<const float4*>(&sgA[idx]);
            *reinterpret_cast<float4*>(&ob[tbA * CC + idx]) = vA;
            float4 vB = *reinterpret_cast<const float4*>(&sgB[idx]);
            *reinterpret_cast<float4*>(&ob[tbB * CC + idx]) = vB;
        }
    }
#undef STEP_LDS
}

extern "C" void kernel_launch(void* const* d_in, const int* in_sizes, int n_in,
                              void* d_out, int out_size, void* d_ws, size_t ws_size,
                              hipStream_t stream) {
    const float* feats = (const float*)d_in[0];
    const float* alpha = (const float*)d_in[1];
    const float* trans = (const float*)d_in[2];
    float* out = (float*)d_out;

    int B = in_sizes[0] / (T_STEPS * CC);   // 8192 (same convention as verified round-0 kernel)

    int threads = B * NQ * 8;               // 8 lanes per (row, chunk-pair)
    int block   = 256;
    int grid    = (threads + block - 1) / block;

    hipLaunchKernelGGL(transfer_kernel, dim3(grid), dim3(block), 0, stream,
                       feats, alpha, trans, out, B);
}